// Round 3
// baseline (720.980 us; speedup 1.0000x reference)
//
#include <hip/hip_runtime.h>

#define Bv 2
#define Nv 2048
#define Cv 512
#define Hv 8
#define Dv 64
#define CAP 256   // candidate cap per row; P(overflow) ~ e^-32 for N(0,1) scores

typedef __attribute__((ext_vector_type(8))) short s16x8;
typedef __attribute__((ext_vector_type(4))) float f32x4;

__device__ __forceinline__ unsigned short f2bf(float f) {
  union { float f; unsigned u; } x; x.f = f;
  return (unsigned short)((x.u + 0x7fffu + ((x.u >> 16) & 1u)) >> 16);
}
__device__ __forceinline__ float bf2f(unsigned short u) {
  union { unsigned u; float f; } x; x.u = ((unsigned)u) << 16;
  return x.f;
}

// ---------------------------------------------------------------------------
// K0: convert x, Wq, Wk, Wv, Wo to bf16 (blockIdx.y selects tensor)
// ---------------------------------------------------------------------------
__global__ __launch_bounds__(256) void cvt5(
    const float* __restrict__ x, const float* __restrict__ wq,
    const float* __restrict__ wk, const float* __restrict__ wv_,
    const float* __restrict__ wo,
    unsigned short* __restrict__ xb, unsigned short* __restrict__ wqb,
    unsigned short* __restrict__ wkb, unsigned short* __restrict__ wvb,
    unsigned short* __restrict__ wob) {
  const float* s; unsigned short* d; int n;
  switch (blockIdx.y) {
    case 0: s = x;   d = xb;  n = Bv * Nv * Cv; break;
    case 1: s = wq;  d = wqb; n = Cv * Cv; break;
    case 2: s = wk;  d = wkb; n = Cv * Cv; break;
    case 3: s = wv_; d = wvb; n = Cv * Cv; break;
    default: s = wo; d = wob; n = Cv * Cv; break;
  }
  int i = (blockIdx.x * 256 + threadIdx.x) * 4;
  if (i < n) {
    float4 v = *(const float4*)(s + i);
    ushort4 o;
    o.x = f2bf(v.x); o.y = f2bf(v.y); o.z = f2bf(v.z); o.w = f2bf(v.w);
    *(ushort4*)(d + i) = o;
  }
}

// ---------------------------------------------------------------------------
// K1: Q/K/V = x @ W^T + b, all bf16 in, bf16 out [B,H,N,D]
// ---------------------------------------------------------------------------
__global__ __launch_bounds__(256) void proj_qkv(
    const unsigned short* __restrict__ xb,
    const unsigned short* __restrict__ wqb, const float* __restrict__ bq,
    const unsigned short* __restrict__ wkb, const float* __restrict__ bk,
    const unsigned short* __restrict__ wvb, const float* __restrict__ bv,
    unsigned short* __restrict__ Qbf, unsigned short* __restrict__ Kbf,
    unsigned short* __restrict__ Vbf) {
  const int lane = threadIdx.x & 63;
  const int wv   = threadIdx.x >> 6;
  const int l16  = lane & 15, quad = lane >> 4;
  const int mbase = blockIdx.x * 64 + wv * 16;
  const int nbase = blockIdx.y * 64;
  const int mat   = blockIdx.z;
  const unsigned short* W = (mat == 0) ? wqb : (mat == 1) ? wkb : wvb;
  const float* bias = (mat == 0) ? bq : (mat == 1) ? bk : bv;
  unsigned short* dst = (mat == 0) ? Qbf : (mat == 1) ? Kbf : Vbf;

  f32x4 acc[4] = {};
  for (int kk = 0; kk < Cv; kk += 32) {
    s16x8 a = *(const s16x8*)(xb + (size_t)(mbase + l16) * Cv + kk + quad * 8);
#pragma unroll
    for (int ct = 0; ct < 4; ct++) {
      s16x8 bfr = *(const s16x8*)(W + (size_t)(nbase + ct * 16 + l16) * Cv + kk + quad * 8);
      acc[ct] = __builtin_amdgcn_mfma_f32_16x16x32_bf16(a, bfr, acc[ct], 0, 0, 0);
    }
  }
#pragma unroll
  for (int ct = 0; ct < 4; ct++) {
    int n = nbase + ct * 16 + l16;
    int h = n >> 6, d = n & 63;
    float bb = bias[n];
#pragma unroll
    for (int r = 0; r < 4; r++) {
      int m = mbase + quad * 4 + r;  // C/D: row=quad*4+reg, col=lane&15
      int bidx = m >> 11, nn = m & 2047;
      dst[(((size_t)bidx * Hv + h) * Nv + nn) * Dv + d] = f2bf(acc[ct][r] + bb);
    }
  }
}

// ---------------------------------------------------------------------------
// K2: sparse fused attention. Per (b,h,16 q-rows):
//  pass A: QK^T row maxes; pass B: compact candidates > max-1 (LDS, cap 256);
//  bisection for tau on candidates; DENSE attn row write built from the
//  candidate list (no memset needed); sparse PV in fp32 VALU; O written bf16.
// ---------------------------------------------------------------------------
__global__ __launch_bounds__(256) void attn_sparse(
    const unsigned short* __restrict__ Qbf, const unsigned short* __restrict__ Kbf,
    const unsigned short* __restrict__ Vbf, float* __restrict__ attn_out,
    unsigned short* __restrict__ Obf) {
  __shared__ float rowmax_w[4][16];
  __shared__ float mrow[16];
  __shared__ float candv[16][CAP];
  __shared__ int   candi[16][CAP];
  __shared__ int   cnt[16];
  __shared__ float lo_s[16], hi_s[16], sum_s[16], taud[16];
  __shared__ int   oflow;

  const int lane = threadIdx.x & 63;
  const int wv   = threadIdx.x >> 6;
  const int l16  = lane & 15, quad = lane >> 4;
  const int bh    = blockIdx.x >> 7;
  const int qbase = (blockIdx.x & 127) << 4;
  const int b = bh >> 3, h = bh & 7;

  const unsigned short* Qh = Qbf + (size_t)bh * Nv * Dv;
  const unsigned short* Kh = Kbf + (size_t)bh * Nv * Dv;
  const unsigned short* Vh = Vbf + (size_t)bh * Nv * Dv;
  float* attn_bh = attn_out + (size_t)bh * Nv * Nv;

  if (threadIdx.x < 16) cnt[threadIdx.x] = 0;
  if (threadIdx.x == 0) oflow = 0;

  s16x8 a0 = *(const s16x8*)(Qh + (size_t)(qbase + l16) * Dv + quad * 8);
  s16x8 a1 = *(const s16x8*)(Qh + (size_t)(qbase + l16) * Dv + 32 + quad * 8);

  // ---- pass A: row maxes (raw dot; scale at end) ----
  float rm[4] = {-1e30f, -1e30f, -1e30f, -1e30f};
  for (int t = 0; t < 32; t++) {
    int col0 = (t * 4 + wv) * 16;
    s16x8 b0 = *(const s16x8*)(Kh + (size_t)(col0 + l16) * Dv + quad * 8);
    s16x8 b1 = *(const s16x8*)(Kh + (size_t)(col0 + l16) * Dv + 32 + quad * 8);
    f32x4 c = {};
    c = __builtin_amdgcn_mfma_f32_16x16x32_bf16(a0, b0, c, 0, 0, 0);
    c = __builtin_amdgcn_mfma_f32_16x16x32_bf16(a1, b1, c, 0, 0, 0);
#pragma unroll
    for (int r = 0; r < 4; r++) rm[r] = fmaxf(rm[r], c[r]);
  }
#pragma unroll
  for (int off = 1; off <= 8; off <<= 1)
#pragma unroll
    for (int r = 0; r < 4; r++) rm[r] = fmaxf(rm[r], __shfl_xor(rm[r], off, 64));
  if (l16 == 0) {
#pragma unroll
    for (int r = 0; r < 4; r++) rowmax_w[wv][quad * 4 + r] = rm[r];
  }
  __syncthreads();
  float m[4];
#pragma unroll
  for (int r = 0; r < 4; r++) {
    int row = quad * 4 + r;
    float mm = fmaxf(fmaxf(rowmax_w[0][row], rowmax_w[1][row]),
                     fmaxf(rowmax_w[2][row], rowmax_w[3][row]));
    m[r] = mm * 0.125f;
  }
  if (wv == 0 && l16 == 0) {
#pragma unroll
    for (int r = 0; r < 4; r++) mrow[quad * 4 + r] = m[r];
  }

  // ---- pass B: compact candidates > max-1 ----
  for (int t = 0; t < 32; t++) {
    int col0 = (t * 4 + wv) * 16;
    s16x8 b0 = *(const s16x8*)(Kh + (size_t)(col0 + l16) * Dv + quad * 8);
    s16x8 b1 = *(const s16x8*)(Kh + (size_t)(col0 + l16) * Dv + 32 + quad * 8);
    f32x4 c = {};
    c = __builtin_amdgcn_mfma_f32_16x16x32_bf16(a0, b0, c, 0, 0, 0);
    c = __builtin_amdgcn_mfma_f32_16x16x32_bf16(a1, b1, c, 0, 0, 0);
#pragma unroll
    for (int r = 0; r < 4; r++) {
      float val = c[r] * 0.125f;
      if (val > m[r] - 1.0f) {
        int row = quad * 4 + r;
        int pos = atomicAdd(&cnt[row], 1);
        if (pos < CAP) { candv[row][pos] = val; candi[row][pos] = col0 + l16; }
      }
    }
  }
  __syncthreads();
  if (threadIdx.x < 16 && cnt[threadIdx.x] > CAP) oflow = 1;
  __syncthreads();

  float tau[4];
  if (oflow == 0) {
    // ---- bisection on candidate lists; wave wv owns rows wv*4..wv*4+3 ----
    float cv[4][4], lo[4], hi[4];
#pragma unroll
    for (int i = 0; i < 4; i++) {
      int row = wv * 4 + i;
      int c_ = cnt[row];
#pragma unroll
      for (int j = 0; j < 4; j++) {
        int p = lane + j * 64;
        cv[i][j] = (p < c_) ? candv[row][p] : -1e30f;
      }
      lo[i] = mrow[row] - 1.0f; hi[i] = mrow[row];
    }
    for (int it = 0; it < 22; it++) {
      float mid[4], s[4];
#pragma unroll
      for (int i = 0; i < 4; i++) {
        mid[i] = 0.5f * (lo[i] + hi[i]);
        float ss = 0.0f;
#pragma unroll
        for (int j = 0; j < 4; j++) ss += fmaxf(cv[i][j] - mid[i], 0.0f);
        s[i] = ss;
      }
#pragma unroll
      for (int off = 32; off > 0; off >>= 1)
#pragma unroll
        for (int i = 0; i < 4; i++) s[i] += __shfl_xor(s[i], off, 64);
#pragma unroll
      for (int i = 0; i < 4; i++) {
        if (s[i] > 1.0f) lo[i] = mid[i]; else hi[i] = mid[i];
      }
    }
#pragma unroll
    for (int i = 0; i < 4; i++) tau[i] = 0.5f * (lo[i] + hi[i]);

    // ---- dense attn row write built from candidate list (replaces memset) --
    // lane owns cols {chunk*256 + lane*4 .. +4}, chunk=0..7 -> coalesced
    // 1 KiB float4 stores per instruction.
#pragma unroll
    for (int i = 0; i < 4; i++) {
      int row = wv * 4 + i;
      float* arow = attn_bh + (size_t)(qbase + row) * Nv;
      int c_ = cnt[row];
#pragma unroll
      for (int ch = 0; ch < 8; ch++) {
        float4 v4 = make_float4(0.f, 0.f, 0.f, 0.f);
        for (int jj = 0; jj < c_; jj++) {
          int idx = candi[row][jj];            // LDS broadcast read
          if ((idx >> 8) == ch && ((idx >> 2) & 63) == lane) {
            float p = fmaxf(candv[row][jj] - tau[i], 0.0f);
            int pos = idx & 3;
            if (pos == 0) v4.x = p;
            else if (pos == 1) v4.y = p;
            else if (pos == 2) v4.z = p;
            else v4.w = p;
          }
        }
        *(float4*)(arow + ch * 256 + lane * 4) = v4;
      }
    }
  } else {
    // ---- pathological fallback: dense bisection via recompute (never taken
    //      for Gaussian-scale inputs; structural correctness only) ----
    if (threadIdx.x < 16) { lo_s[threadIdx.x] = mrow[threadIdx.x] - 1.0f; hi_s[threadIdx.x] = mrow[threadIdx.x]; }
    __syncthreads();
    for (int it = 0; it < 26; it++) {
      if (threadIdx.x < 16) sum_s[threadIdx.x] = 0.0f;
      __syncthreads();
      float part[4] = {0, 0, 0, 0};
      for (int t = 0; t < 32; t++) {
        int col0 = (t * 4 + wv) * 16;
        s16x8 b0 = *(const s16x8*)(Kh + (size_t)(col0 + l16) * Dv + quad * 8);
        s16x8 b1 = *(const s16x8*)(Kh + (size_t)(col0 + l16) * Dv + 32 + quad * 8);
        f32x4 c = {};
        c = __builtin_amdgcn_mfma_f32_16x16x32_bf16(a0, b0, c, 0, 0, 0);
        c = __builtin_amdgcn_mfma_f32_16x16x32_bf16(a1, b1, c, 0, 0, 0);
#pragma unroll
        for (int r = 0; r < 4; r++) {
          int row = quad * 4 + r;
          float mid = 0.5f * (lo_s[row] + hi_s[row]);
          part[r] += fmaxf(c[r] * 0.125f - mid, 0.0f);
        }
      }
#pragma unroll
      for (int off = 1; off <= 8; off <<= 1)
#pragma unroll
        for (int r = 0; r < 4; r++) part[r] += __shfl_xor(part[r], off, 64);
      if (l16 == 0) {
#pragma unroll
        for (int r = 0; r < 4; r++) atomicAdd(&sum_s[quad * 4 + r], part[r]);
      }
      __syncthreads();
      if (threadIdx.x < 16) {
        float mid = 0.5f * (lo_s[threadIdx.x] + hi_s[threadIdx.x]);
        if (sum_s[threadIdx.x] > 1.0f) lo_s[threadIdx.x] = mid; else hi_s[threadIdx.x] = mid;
      }
      __syncthreads();
    }
    if (threadIdx.x < 16) taud[threadIdx.x] = 0.5f * (lo_s[threadIdx.x] + hi_s[threadIdx.x]);
    __syncthreads();
    // dense attn write
    for (int t = 0; t < 32; t++) {
      int col0 = (t * 4 + wv) * 16;
      s16x8 b0 = *(const s16x8*)(Kh + (size_t)(col0 + l16) * Dv + quad * 8);
      s16x8 b1 = *(const s16x8*)(Kh + (size_t)(col0 + l16) * Dv + 32 + quad * 8);
      f32x4 c = {};
      c = __builtin_amdgcn_mfma_f32_16x16x32_bf16(a0, b0, c, 0, 0, 0);
      c = __builtin_amdgcn_mfma_f32_16x16x32_bf16(a1, b1, c, 0, 0, 0);
#pragma unroll
      for (int r = 0; r < 4; r++) {
        int row = quad * 4 + r;
        attn_bh[(size_t)(qbase + row) * Nv + col0 + l16] =
            fmaxf(c[r] * 0.125f - taud[row], 0.0f);
      }
    }
    __threadfence();
    __syncthreads();
#pragma unroll
    for (int i = 0; i < 4; i++) tau[i] = taud[wv * 4 + i];
  }

  // ---- sparse PV (fp32 VALU); lane = output dim ----
  float o[4] = {0, 0, 0, 0};
  if (oflow == 0) {
#pragma unroll
    for (int i = 0; i < 4; i++) {
      int row = wv * 4 + i;
      int c_ = cnt[row] < CAP ? cnt[row] : CAP;
      for (int jj = 0; jj < c_; jj++) {
        float p = candv[row][jj] - tau[i];
        if (p > 0.0f) {
          int k = candi[row][jj];
          o[i] += p * bf2f(Vh[(size_t)k * Dv + lane]);
        }
      }
    }
  } else {
    // slow, correct: read back dense attn row (never taken in practice)
#pragma unroll
    for (int i = 0; i < 4; i++) {
      int row = wv * 4 + i;
      const float* arow = attn_bh + (size_t)(qbase + row) * Nv;
      for (int k = 0; k < Nv; k++) {
        float p = arow[k];
        if (p > 0.0f) o[i] += p * bf2f(Vh[(size_t)k * Dv + lane]);
      }
    }
  }
#pragma unroll
  for (int i = 0; i < 4; i++) {
    int row = wv * 4 + i;
    Obf[((size_t)(b * Nv + qbase + row)) * Cv + h * Dv + lane] = f2bf(o[i]);
  }
}

// ---------------------------------------------------------------------------
// K3: out = O @ Wo^T + bo (bf16 in, fp32 out)
// ---------------------------------------------------------------------------
__global__ __launch_bounds__(256) void proj_out(
    const unsigned short* __restrict__ Obf, const unsigned short* __restrict__ wob,
    const float* __restrict__ bo, float* __restrict__ out) {
  const int lane = threadIdx.x & 63;
  const int wv   = threadIdx.x >> 6;
  const int l16  = lane & 15, quad = lane >> 4;
  const int mbase = blockIdx.x * 64 + wv * 16;
  const int nbase = blockIdx.y * 64;

  f32x4 acc[4] = {};
  for (int kk = 0; kk < Cv; kk += 32) {
    s16x8 a = *(const s16x8*)(Obf + (size_t)(mbase + l16) * Cv + kk + quad * 8);
#pragma unroll
    for (int ct = 0; ct < 4; ct++) {
      s16x8 bfr = *(const s16x8*)(wob + (size_t)(nbase + ct * 16 + l16) * Cv + kk + quad * 8);
      acc[ct] = __builtin_amdgcn_mfma_f32_16x16x32_bf16(a, bfr, acc[ct], 0, 0, 0);
    }
  }
#pragma unroll
  for (int ct = 0; ct < 4; ct++) {
    int n = nbase + ct * 16 + l16;
    float bb = bo[n];
#pragma unroll
    for (int r = 0; r < 4; r++) {
      int m = mbase + quad * 4 + r;
      out[(size_t)m * Cv + n] = acc[ct][r] + bb;
    }
  }
}

extern "C" void kernel_launch(void* const* d_in, const int* in_sizes, int n_in,
                              void* d_out, int out_size, void* d_ws, size_t ws_size,
                              hipStream_t stream) {
  (void)in_sizes; (void)n_in; (void)out_size; (void)ws_size;
  const float* x  = (const float*)d_in[0];
  const float* Wq = (const float*)d_in[1];
  const float* bq = (const float*)d_in[2];
  const float* Wk = (const float*)d_in[3];
  const float* bk = (const float*)d_in[4];
  const float* Wv = (const float*)d_in[5];
  const float* bv = (const float*)d_in[6];
  const float* Wo = (const float*)d_in[7];
  const float* bo = (const float*)d_in[8];

  float* out  = (float*)d_out;                       // [B,N,C]
  float* attn = out + (size_t)Bv * Nv * Cv;          // [B,H,N,N]

  unsigned short* xb  = (unsigned short*)d_ws;
  unsigned short* wqb = xb  + (size_t)Bv * Nv * Cv;  // +2097152
  unsigned short* wkb = wqb + (size_t)Cv * Cv;
  unsigned short* wvb = wkb + (size_t)Cv * Cv;
  unsigned short* wob = wvb + (size_t)Cv * Cv;
  unsigned short* Qbf = wob + (size_t)Cv * Cv;
  unsigned short* Kbf = Qbf + (size_t)Bv * Hv * Nv * Dv;
  unsigned short* Vbf = Kbf + (size_t)Bv * Hv * Nv * Dv;
  unsigned short* Obf = Vbf + (size_t)Bv * Hv * Nv * Dv;

  cvt5<<<dim3((Bv * Nv * Cv) / 4 / 256, 5), 256, 0, stream>>>(
      x, Wq, Wk, Wv, Wo, xb, wqb, wkb, wvb, wob);
  proj_qkv<<<dim3((Bv * Nv) / 64, Cv / 64, 3), 256, 0, stream>>>(
      xb, wqb, bq, wkb, bk, wvb, bv, Qbf, Kbf, Vbf);
  attn_sparse<<<dim3(Bv * Hv * (Nv / 16)), 256, 0, stream>>>(
      Qbf, Kbf, Vbf, attn, Obf);
  proj_out<<<dim3((Bv * Nv) / 64, Cv / 64), 256, 0, stream>>>(Obf, wob, bo, out);
}